// Round 1
// baseline (1512.759 us; speedup 1.0000x reference)
//
#include <hip/hip_runtime.h>

typedef __bf16 bf16_t;
typedef bf16_t bf16x8 __attribute__((ext_vector_type(8)));
typedef float f32x4 __attribute__((ext_vector_type(4)));

constexpr int DIM      = 128;
constexpr int FANOUT   = 5;
constexpr int NUM_EDGE = 20000;
constexpr int NUM_DST1 = 60000;    // (NEG+2)*NUM_EDGE
constexpr int NUM_DST0 = 360000;   // NUM_DST1*6

// ---------------------------------------------------------------------------
// Stage 1: h = relu(x[:360000] @ Wself0^T + mean5(x[src0]) @ Wneigh0^T + b0)
// Output bf16. Weights [Wself|Wneigh] (K=256) staged bf16 in 64KB LDS,
// XOR-swizzled 16B chunks so B-frag ds_read_b128 is ~2-way (free).
// ---------------------------------------------------------------------------
__global__ __launch_bounds__(512, 4) void k_layer0(
    const float* __restrict__ x, const float* __restrict__ Wself,
    const float* __restrict__ Wneigh, const float* __restrict__ bias,
    const int* __restrict__ src, unsigned short* __restrict__ hout)
{
    __shared__ char smem[65536];
    const int tid = threadIdx.x;
    // stage Wcat[n][k] (n=0..127, k=0..255) as 32 chunks of 8 bf16 per row
    for (int idx = tid; idx < 128 * 32; idx += 512) {
        const int n = idx >> 5, c = idx & 31;
        const float* sp = (c < 16) ? (Wself + n * 128 + c * 8)
                                   : (Wneigh + n * 128 + (c - 16) * 8);
        bf16x8 v;
#pragma unroll
        for (int j = 0; j < 8; ++j) v[j] = (bf16_t)sp[j];
        *(bf16x8*)(smem + n * 512 + ((c ^ (n & 7)) << 4)) = v;
    }
    __syncthreads();

    const int lane = tid & 63;
    const int wv   = tid >> 6;
    const int n    = lane & 15;   // A-row within tile / B-col within tile
    const int q    = lane >> 4;   // quad
    const int tile = blockIdx.x * 8 + wv;
    if (tile >= NUM_DST0 / 16) return;
    const int d = tile * 16 + n;

    int sidx[FANOUT];
#pragma unroll
    for (int r = 0; r < FANOUT; ++r) sidx[r] = src[d * FANOUT + r];

    bf16x8 afrag[8];                       // [0..3]=self, [4..7]=neigh
    const float* xrow = x + (long)d * DIM;
#pragma unroll
    for (int s = 0; s < 4; ++s) {
        const int k0 = s * 32 + q * 8;
        f32x4 u0 = *(const f32x4*)(xrow + k0);
        f32x4 u1 = *(const f32x4*)(xrow + k0 + 4);
        bf16x8 v;
#pragma unroll
        for (int j = 0; j < 4; ++j) { v[j] = (bf16_t)u0[j]; v[4 + j] = (bf16_t)u1[j]; }
        afrag[s] = v;
    }
#pragma unroll
    for (int s = 0; s < 4; ++s) {
        const int k0 = s * 32 + q * 8;
        float an[8];
#pragma unroll
        for (int j = 0; j < 8; ++j) an[j] = 0.f;
#pragma unroll
        for (int r = 0; r < FANOUT; ++r) {
            const float* srow = x + (long)sidx[r] * DIM;
            f32x4 u0 = *(const f32x4*)(srow + k0);
            f32x4 u1 = *(const f32x4*)(srow + k0 + 4);
#pragma unroll
            for (int j = 0; j < 4; ++j) { an[j] += u0[j]; an[4 + j] += u1[j]; }
        }
        bf16x8 v;
#pragma unroll
        for (int j = 0; j < 8; ++j) v[j] = (bf16_t)(an[j] * 0.2f);
        afrag[4 + s] = v;
    }

    f32x4 acc[8];
#pragma unroll
    for (int t = 0; t < 8; ++t) acc[t] = (f32x4)(0.0f);
#pragma unroll
    for (int s = 0; s < 8; ++s) {
        const int c = 4 * s + q;           // k-chunk index 0..31
#pragma unroll
        for (int t = 0; t < 8; ++t) {
            const int row = 16 * t + n;
            bf16x8 bfrag = *(const bf16x8*)(smem + row * 512 + ((c ^ (row & 7)) << 4));
            acc[t] = __builtin_amdgcn_mfma_f32_16x16x32_bf16(afrag[s], bfrag, acc[t], 0, 0, 0);
        }
    }

    const long rowbase = (long)tile * 16 + q * 4;   // C-layout: row = quad*4+r
#pragma unroll
    for (int t = 0; t < 8; ++t) {
        const float bv = bias[16 * t + n];
#pragma unroll
        for (int r = 0; r < 4; ++r) {
            float v = acc[t][r] + bv;
            v = v > 0.f ? v : 0.f;
            hout[(rowbase + r) * DIM + 16 * t + n] =
                __builtin_bit_cast(unsigned short, (bf16_t)v);
        }
    }
}

// ---------------------------------------------------------------------------
// Stage 2: h1 = h[:60000] @ Wself1^T + mean5(h[src1]) @ Wneigh1^T + b1 (no relu)
// Input/output bf16.
// ---------------------------------------------------------------------------
__global__ __launch_bounds__(512, 4) void k_layer1(
    const unsigned short* __restrict__ h, const float* __restrict__ Wself,
    const float* __restrict__ Wneigh, const float* __restrict__ bias,
    const int* __restrict__ src, unsigned short* __restrict__ hout)
{
    __shared__ char smem[65536];
    const int tid = threadIdx.x;
    for (int idx = tid; idx < 128 * 32; idx += 512) {
        const int n = idx >> 5, c = idx & 31;
        const float* sp = (c < 16) ? (Wself + n * 128 + c * 8)
                                   : (Wneigh + n * 128 + (c - 16) * 8);
        bf16x8 v;
#pragma unroll
        for (int j = 0; j < 8; ++j) v[j] = (bf16_t)sp[j];
        *(bf16x8*)(smem + n * 512 + ((c ^ (n & 7)) << 4)) = v;
    }
    __syncthreads();

    const int lane = tid & 63;
    const int wv   = tid >> 6;
    const int n    = lane & 15;
    const int q    = lane >> 4;
    const int tile = blockIdx.x * 8 + wv;
    if (tile >= NUM_DST1 / 16) return;
    const int d = tile * 16 + n;

    int sidx[FANOUT];
#pragma unroll
    for (int r = 0; r < FANOUT; ++r) sidx[r] = src[d * FANOUT + r];

    bf16x8 afrag[8];
#pragma unroll
    for (int s = 0; s < 4; ++s)
        afrag[s] = *(const bf16x8*)(h + (long)d * DIM + s * 32 + q * 8);
#pragma unroll
    for (int s = 0; s < 4; ++s) {
        float an[8];
#pragma unroll
        for (int j = 0; j < 8; ++j) an[j] = 0.f;
#pragma unroll
        for (int r = 0; r < FANOUT; ++r) {
            bf16x8 u = *(const bf16x8*)(h + (long)sidx[r] * DIM + s * 32 + q * 8);
#pragma unroll
            for (int j = 0; j < 8; ++j) an[j] += (float)u[j];
        }
        bf16x8 v;
#pragma unroll
        for (int j = 0; j < 8; ++j) v[j] = (bf16_t)(an[j] * 0.2f);
        afrag[4 + s] = v;
    }

    f32x4 acc[8];
#pragma unroll
    for (int t = 0; t < 8; ++t) acc[t] = (f32x4)(0.0f);
#pragma unroll
    for (int s = 0; s < 8; ++s) {
        const int c = 4 * s + q;
#pragma unroll
        for (int t = 0; t < 8; ++t) {
            const int row = 16 * t + n;
            bf16x8 bfrag = *(const bf16x8*)(smem + row * 512 + ((c ^ (row & 7)) << 4));
            acc[t] = __builtin_amdgcn_mfma_f32_16x16x32_bf16(afrag[s], bfrag, acc[t], 0, 0, 0);
        }
    }

    const long rowbase = (long)tile * 16 + q * 4;
#pragma unroll
    for (int t = 0; t < 8; ++t) {
        const float bv = bias[16 * t + n];
#pragma unroll
        for (int r = 0; r < 4; ++r) {
            float v = acc[t][r] + bv;   // no relu
            hout[(rowbase + r) * DIM + 16 * t + n] =
                __builtin_bit_cast(unsigned short, (bf16_t)v);
        }
    }
}

// ---------------------------------------------------------------------------
// Stage 3a: hmid = relu( (h1[r%20000] * h1[r+20000]) @ Wp1^T + bp1 ), r=0..40000
// ---------------------------------------------------------------------------
__global__ __launch_bounds__(256, 4) void k_pred1(
    const unsigned short* __restrict__ h1, const float* __restrict__ Wp1,
    const float* __restrict__ bp1, unsigned short* __restrict__ hmid)
{
    __shared__ char smem[32768];
    const int tid = threadIdx.x;
    for (int idx = tid; idx < 128 * 16; idx += 256) {
        const int n = idx >> 4, c = idx & 15;
        const float* sp = Wp1 + n * 128 + c * 8;
        bf16x8 v;
#pragma unroll
        for (int j = 0; j < 8; ++j) v[j] = (bf16_t)sp[j];
        *(bf16x8*)(smem + n * 256 + ((c ^ (n & 7)) << 4)) = v;
    }
    __syncthreads();

    const int lane = tid & 63;
    const int n    = lane & 15;
    const int q    = lane >> 4;
    const int tile = blockIdx.x * 4 + (tid >> 6);   // 2500 tiles exactly
    const int row  = tile * 16 + n;
    const int ra   = (row < NUM_EDGE) ? row : row - NUM_EDGE;
    const int rb   = row + NUM_EDGE;

    bf16x8 afrag[4];
#pragma unroll
    for (int s = 0; s < 4; ++s) {
        bf16x8 ua = *(const bf16x8*)(h1 + (long)ra * DIM + s * 32 + q * 8);
        bf16x8 ub = *(const bf16x8*)(h1 + (long)rb * DIM + s * 32 + q * 8);
        bf16x8 v;
#pragma unroll
        for (int j = 0; j < 8; ++j) v[j] = (bf16_t)((float)ua[j] * (float)ub[j]);
        afrag[s] = v;
    }

    f32x4 acc[8];
#pragma unroll
    for (int t = 0; t < 8; ++t) acc[t] = (f32x4)(0.0f);
#pragma unroll
    for (int s = 0; s < 4; ++s) {
        const int c = 4 * s + q;
#pragma unroll
        for (int t = 0; t < 8; ++t) {
            const int rw = 16 * t + n;
            bf16x8 bfrag = *(const bf16x8*)(smem + rw * 256 + ((c ^ (rw & 7)) << 4));
            acc[t] = __builtin_amdgcn_mfma_f32_16x16x32_bf16(afrag[s], bfrag, acc[t], 0, 0, 0);
        }
    }

    const long rowbase = (long)tile * 16 + q * 4;
#pragma unroll
    for (int t = 0; t < 8; ++t) {
        const float bv = bp1[16 * t + n];
#pragma unroll
        for (int r = 0; r < 4; ++r) {
            float v = acc[t][r] + bv;
            v = v > 0.f ? v : 0.f;
            hmid[(rowbase + r) * DIM + 16 * t + n] =
                __builtin_bit_cast(unsigned short, (bf16_t)v);
        }
    }
}

// ---------------------------------------------------------------------------
// Stage 3b: out = relu(hmid @ Wp2^T + bp2) @ Wp3^T + bp3  (fused P2+P3)
// ---------------------------------------------------------------------------
__global__ __launch_bounds__(256, 4) void k_pred2(
    const unsigned short* __restrict__ hmid, const float* __restrict__ Wp2,
    const float* __restrict__ bp2, const float* __restrict__ Wp3,
    const float* __restrict__ bp3, float* __restrict__ out)
{
    __shared__ char smem[32768];
    const int tid = threadIdx.x;
    for (int idx = tid; idx < 128 * 16; idx += 256) {
        const int n = idx >> 4, c = idx & 15;
        const float* sp = Wp2 + n * 128 + c * 8;
        bf16x8 v;
#pragma unroll
        for (int j = 0; j < 8; ++j) v[j] = (bf16_t)sp[j];
        *(bf16x8*)(smem + n * 256 + ((c ^ (n & 7)) << 4)) = v;
    }
    __syncthreads();

    const int lane = tid & 63;
    const int n    = lane & 15;
    const int q    = lane >> 4;
    const int tile = blockIdx.x * 4 + (tid >> 6);
    const int row  = tile * 16 + n;

    bf16x8 afrag[4];
#pragma unroll
    for (int s = 0; s < 4; ++s)
        afrag[s] = *(const bf16x8*)(hmid + (long)row * DIM + s * 32 + q * 8);

    f32x4 acc[8];
#pragma unroll
    for (int t = 0; t < 8; ++t) acc[t] = (f32x4)(0.0f);
#pragma unroll
    for (int s = 0; s < 4; ++s) {
        const int c = 4 * s + q;
#pragma unroll
        for (int t = 0; t < 8; ++t) {
            const int rw = 16 * t + n;
            bf16x8 bfrag = *(const bf16x8*)(smem + rw * 256 + ((c ^ (rw & 7)) << 4));
            acc[t] = __builtin_amdgcn_mfma_f32_16x16x32_bf16(afrag[s], bfrag, acc[t], 0, 0, 0);
        }
    }

    float osum[4] = {0.f, 0.f, 0.f, 0.f};
#pragma unroll
    for (int t = 0; t < 8; ++t) {
        const float b2 = bp2[16 * t + n];
        const float w3 = Wp3[16 * t + n];
#pragma unroll
        for (int r = 0; r < 4; ++r) {
            float v = acc[t][r] + b2;
            v = v > 0.f ? v : 0.f;
            osum[r] += v * w3;
        }
    }
    // reduce over the 16 column-lanes (n = lane&15)
#pragma unroll
    for (int m = 1; m <= 8; m <<= 1) {
#pragma unroll
        for (int r = 0; r < 4; ++r) osum[r] += __shfl_xor(osum[r], m, 64);
    }
    if (n == 0) {
        const float b3 = bp3[0];
#pragma unroll
        for (int r = 0; r < 4; ++r) out[tile * 16 + q * 4 + r] = osum[r] + b3;
    }
}

// ---------------------------------------------------------------------------
extern "C" void kernel_launch(void* const* d_in, const int* in_sizes, int n_in,
                              void* d_out, int out_size, void* d_ws, size_t ws_size,
                              hipStream_t stream) {
    const float* x       = (const float*)d_in[0];
    const float* Wself0  = (const float*)d_in[1];
    const float* Wneigh0 = (const float*)d_in[2];
    const float* b0      = (const float*)d_in[3];
    const float* Wself1  = (const float*)d_in[4];
    const float* Wneigh1 = (const float*)d_in[5];
    const float* b1      = (const float*)d_in[6];
    const float* Wp1     = (const float*)d_in[7];
    const float* bp1     = (const float*)d_in[8];
    const float* Wp2     = (const float*)d_in[9];
    const float* bp2     = (const float*)d_in[10];
    const float* Wp3     = (const float*)d_in[11];
    const float* bp3     = (const float*)d_in[12];
    const int*   src0    = (const int*)d_in[13];
    const int*   src1    = (const int*)d_in[15];
    // d_in[14]=dst0, d_in[16]=dst1 are repeat(arange,FANOUT): deg==5 exactly.

    // workspace: h bf16 (92.16MB), h1 bf16 (15.36MB); hmid reuses h's region.
    unsigned short* h    = (unsigned short*)d_ws;
    unsigned short* h1   = h + (size_t)NUM_DST0 * DIM;
    unsigned short* hmid = (unsigned short*)d_ws;   // h is dead after k_layer1

    k_layer0<<<dim3((NUM_DST0 / 16 + 7) / 8), dim3(512), 0, stream>>>(
        x, Wself0, Wneigh0, b0, src0, h);
    k_layer1<<<dim3((NUM_DST1 / 16 + 7) / 8), dim3(512), 0, stream>>>(
        h, Wself1, Wneigh1, b1, src1, h1);
    k_pred1<<<dim3(625), dim3(256), 0, stream>>>(h1, Wp1, bp1, hmid);
    k_pred2<<<dim3(625), dim3(256), 0, stream>>>(hmid, Wp2, bp2, Wp3, bp3,
                                                 (float*)d_out);
}